// Round 12
// baseline (6134.579 us; speedup 1.0000x reference)
//
#include <hip/hip_runtime.h>
#include <hip/hip_fp16.h>
#include <cstdint>
#include <cstddef>

typedef _Float16 f16;
typedef _Float16 f16x8 __attribute__((ext_vector_type(8)));
typedef _Float16 f16x4 __attribute__((ext_vector_type(4)));
typedef float    f32x4 __attribute__((ext_vector_type(4)));

// ---------------- ws layout (bytes) ----------------
// Gs   f32 [2048][10]                :      0 ..  81920
// QM   f32 [10][16]                  :  81920 ..  82560
// CB   f32 [10][16]                  :  82560 ..  83200
// W1T  f16 [16][5][4][80]            :  83200 .. 134400   (dead after k1)
//   hx  u64 [4][1216]   (overlay)    :  83200 .. 122112   (sentinel exchange)
// WhhP f16 [57*10][64][8]            : 134400 .. 718080
// giP  f16 [2048][57][64][4]         : 718080 .. 60486912
#define WS_GS    0u
#define WS_QM    81920u
#define WS_CB    82560u
#define WS_W1T   83200u
#define WS_HX    83200u
#define WS_WHHP  134400u
#define WS_GIP   718080u

#define HPAR 1216        // u64 per parity: 76 cg * 16 bl
#define SENT 0xFFFFFFFFFFFFFFFFull
#define SPIN_ROUNDS 200000

__device__ __forceinline__ float sigm_(float x){ return 1.0f/(1.0f + __expf(-x)); }
__device__ __forceinline__ float tanh_(float x){
  float ax = fabsf(x);
  float e  = __expf(-2.0f*ax);
  float r  = (1.0f - e)/(1.0f + e);
  return x < 0.0f ? -r : r;
}
__device__ __forceinline__ int imin_(int a,int b){ return a<b?a:b; }

// ================= K0: prep (QM, CB, W1T) =================
__global__ __launch_bounds__(512) void k0_prep(
    const float* __restrict__ q, const float* __restrict__ m,
    const float* __restrict__ W1, const float* __restrict__ b1,
    float* __restrict__ QM, float* __restrict__ CBo, f16* __restrict__ W1T)
{
  int tid = threadIdx.x;
  if (tid < 160){
    int k = tid >> 4, h = tid & 15;
    float acc = 0.f;
    for (int d = 0; d < 300; ++d)
      acc += q[k*300+d]*W1[(2100+d)*16+h] + m[k*300+d]*W1[(2400+d)*16+h];
    QM[tid] = acc;
  } else if (tid < 320){
    int b = (tid-160) >> 4, h = tid & 15;
    float acc = b1[h];
    for (int d = 0; d < 300; ++d)
      acc += m[b*300+d]*W1[(300+d)*16+h] + q[b*300+d]*W1[(600+d)*16+h];
    CBo[tid-160] = acc;
  }
  const int blkoff[5] = {0, 900, 1200, 1500, 1800};
  for (int i = tid; i < 25600; i += 512){
    int ii = i % 80; int r = i / 80;
    int dg = r % 4; r /= 4;
    int blk = r % 5; int h = r / 5;
    int d = dg*80 + ii;
    float v = 0.f;
    if (d < 300) v = W1[(blkoff[blk]+d)*16 + h];
    W1T[i] = (f16)v;
  }
}

// ================= Kpack: Whh -> MFMA A-fragment layout (f16) =================
__global__ __launch_bounds__(64) void k_pack(const float* __restrict__ Whh, f16* __restrict__ WhhP)
{
  int bid = blockIdx.x, l = threadIdx.x;
  int mt = bid / 10, kc = bid % 10;
  int gate = mt / 19, cb = mt % 19;
  int rr = l & 15, grp = l >> 4;
  int c = cb*16 + rr;
  int j = gate*300 + imin_(c, 299);
  f16x8 v;
  #pragma unroll
  for (int e = 0; e < 8; ++e){
    int d = kc*32 + grp*8 + e;
    float x = Whh[(size_t)imin_(d,299)*900 + j];
    v[e] = (f16)((d < 300 && c < 300) ? x : 0.f);
  }
  *(f16x8*)&WhhP[((size_t)bid*64 + l)*8] = v;
}

// ================= K1: attention gate -> G[b][t] (d_out[0:20480]) =================
__global__ __launch_bounds__(512) void k1_attn(
    const float* __restrict__ cs, const float* __restrict__ mI, const float* __restrict__ qI,
    const float* __restrict__ mask, const float* __restrict__ Wb,
    const float* __restrict__ W2, const float* __restrict__ b2,
    const float* __restrict__ QMg, const float* __restrict__ CBg, const f16* __restrict__ W1Tg,
    float* __restrict__ Gout)
{
  __shared__ __align__(16) float q_s[3000];
  __shared__ __align__(16) float m_s[3000];
  __shared__ float Wb_s[3000];
  __shared__ float QM_s[160], CB_s[160], W2_s[16];
  __shared__ __align__(16) f16 W1T_s[25600];
  __shared__ float cwb_s[8][10][10];
  int tid = threadIdx.x;
  for (int i = tid; i < 3000; i += 512){ q_s[i] = qI[i]; m_s[i] = mI[i]; Wb_s[i] = Wb[i]; }
  for (int i = tid; i < 160; i += 512){ QM_s[i] = QMg[i]; CB_s[i] = CBg[i]; }
  if (tid < 16) W2_s[tid] = W2[tid];
  for (int i = tid; i < 25600; i += 512) W1T_s[i] = W1Tg[i];
  __syncthreads();

  int w = tid >> 6, l = tid & 63, dg = l >> 4, lo = l & 15;
  int t = blockIdx.x*8 + w;
  float a[10], cwb[10];
  #pragma unroll
  for (int b = 0; b < 10; ++b){ a[b] = 0.f; cwb[b] = 0.f; }

  for (int i = 0; i < 10; ++i){
    int d0 = dg*80 + i*8;
    const int wbase = lo*1600 + dg*80 + i*8;
    f16x8 wf0 = *(const f16x8*)&W1T_s[wbase + 0*320];
    f16x8 wf1 = *(const f16x8*)&W1T_s[wbase + 1*320];
    f16x8 wf2 = *(const f16x8*)&W1T_s[wbase + 2*320];
    f16x8 wf3 = *(const f16x8*)&W1T_s[wbase + 3*320];
    f16x8 wf4 = *(const f16x8*)&W1T_s[wbase + 4*320];
    int dc0 = imin_(d0, 296), dc1 = imin_(d0 + 4, 296);
    #pragma unroll
    for (int b = 0; b < 10; ++b){
      const float* csb = cs + ((size_t)t*10 + b)*300;
      float4 c0 = *(const float4*)(csb + dc0);
      float4 c1 = *(const float4*)(csb + dc1);
      float4 q0 = *(const float4*)(q_s + b*300 + dc0);
      float4 q1 = *(const float4*)(q_s + b*300 + dc1);
      float4 m0 = *(const float4*)(m_s + b*300 + dc0);
      float4 m1 = *(const float4*)(m_s + b*300 + dc1);
      float cv[8] = {c0.x,c0.y,c0.z,c0.w,c1.x,c1.y,c1.z,c1.w};
      float qv[8] = {q0.x,q0.y,q0.z,q0.w,q1.x,q1.y,q1.z,q1.w};
      float mv[8] = {m0.x,m0.y,m0.z,m0.w,m1.x,m1.y,m1.z,m1.w};
      #pragma unroll
      for (int e = 0; e < 8; ++e){
        int d = d0 + e;
        float cvv = cv[e];
        a[b] += cvv*(float)wf0[e] + (cvv*qv[e])*(float)wf1[e] + (cvv*mv[e])*(float)wf2[e]
              + fabsf(cvv - qv[e])*(float)wf3[e] + fabsf(cvv - mv[e])*(float)wf4[e];
        float wv = Wb_s[imin_(d, 299)*10 + imin_(lo, 9)];
        wv = (lo < 10 && d < 300) ? wv : 0.f;
        cwb[b] += cvv*wv;
      }
    }
  }
  #pragma unroll
  for (int b = 0; b < 10; ++b){
    float v = cwb[b];
    v += __shfl_xor(v, 16, 64);
    v += __shfl_xor(v, 32, 64);
    cwb[b] = v;
  }
  if (dg == 0 && lo < 10){
    #pragma unroll
    for (int b = 0; b < 10; ++b) cwb_s[w][b][lo] = cwb[b];
  }
  __asm__ volatile("s_waitcnt lgkmcnt(0)" ::: "memory");
  __builtin_amdgcn_sched_barrier(0);
  float b2v = b2[0];
  #pragma unroll
  for (int b = 0; b < 10; ++b){
    float cross = 0.f;
    #pragma unroll
    for (int k = 0; k < 10; ++k) cross += cwb_s[w][b][k]*QM_s[k*16 + lo];
    float v = a[b];
    v += __shfl_xor(v, 16, 64);
    v += __shfl_xor(v, 32, 64);
    v += CB_s[b*16 + lo] + cross;
    float tv = tanh_(v)*W2_s[lo];
    tv += __shfl_xor(tv, 1, 64);
    tv += __shfl_xor(tv, 2, 64);
    tv += __shfl_xor(tv, 4, 64);
    tv += __shfl_xor(tv, 8, 64);
    a[b] = sigm_(tv + b2v);
  }
  if (l == 0){
    #pragma unroll
    for (int b = 0; b < 10; ++b) Gout[b*2048 + t] = a[b]*mask[t*10 + b];
  }
}

// ================= K2: softmax over T per b: Gs[t][b] =================
__global__ __launch_bounds__(256) void k2_softmax(const float* __restrict__ G, float* __restrict__ Gs)
{
  int b = blockIdx.x, tid = threadIdx.x;
  __shared__ float red[4];
  float v[8];
  #pragma unroll
  for (int k = 0; k < 8; ++k) v[k] = G[b*2048 + tid + k*256];
  float mx = v[0];
  #pragma unroll
  for (int k = 1; k < 8; ++k) mx = fmaxf(mx, v[k]);
  #pragma unroll
  for (int off = 1; off < 64; off <<= 1) mx = fmaxf(mx, __shfl_xor(mx, off, 64));
  if ((tid & 63) == 0) red[tid >> 6] = mx;
  __syncthreads();
  mx = fmaxf(fmaxf(red[0], red[1]), fmaxf(red[2], red[3]));
  __syncthreads();
  float e[8], s = 0.f;
  #pragma unroll
  for (int k = 0; k < 8; ++k){ e[k] = __expf(v[k]-mx); s += e[k]; }
  #pragma unroll
  for (int off = 1; off < 64; off <<= 1) s += __shfl_xor(s, off, 64);
  if ((tid & 63) == 0) red[tid >> 6] = s;
  __syncthreads();
  s = red[0]+red[1]+red[2]+red[3];
  float inv = 1.0f / s;
  #pragma unroll
  for (int k = 0; k < 8; ++k) Gs[(tid + k*256)*10 + b] = e[k]*inv;
}

// ================= K3: gi[t] = seq[t] @ Wih + bih (+bhh folded for r,z) =================
__global__ __launch_bounds__(256) void k3_gi(
    const float* __restrict__ cs, const float* __restrict__ Gs,
    const float* __restrict__ Wih, const float* __restrict__ bih, const float* __restrict__ bhh,
    f16* __restrict__ giP)
{
  int t = blockIdx.x, tid = threadIdx.x;
  __shared__ __align__(16) float sfT[300*16];
  for (int i = tid; i < 3000; i += 256){
    int d = i / 10, bcol = i % 10;
    int jj = d % 10;
    sfT[d*16 + bcol] = Gs[t*10 + jj] * cs[((size_t)t*10 + jj)*300 + bcol*30 + d/10];
  }
  __syncthreads();
  float acc[4][10];
  #pragma unroll
  for (int jp = 0; jp < 4; ++jp)
    #pragma unroll
    for (int b = 0; b < 10; ++b) acc[jp][b] = 0.f;
  for (int d = 0; d < 300; ++d){
    float4 s0 = *(const float4*)&sfT[d*16 + 0];
    float4 s1 = *(const float4*)&sfT[d*16 + 4];
    float4 s2 = *(const float4*)&sfT[d*16 + 8];
    float sb[10] = {s0.x,s0.y,s0.z,s0.w, s1.x,s1.y,s1.z,s1.w, s2.x,s2.y};
    #pragma unroll
    for (int jp = 0; jp < 4; ++jp){
      int j = jp*256 + tid;
      float wv = Wih[(size_t)d*900 + imin_(j, 899)];
      wv = (j < 900) ? wv : 0.f;
      #pragma unroll
      for (int b = 0; b < 10; ++b) acc[jp][b] += wv * sb[b];
    }
  }
  #pragma unroll
  for (int jp = 0; jp < 4; ++jp){
    int j = jp*256 + tid;
    if (j < 900){
      int gate = j / 300, c = j - gate*300;
      int cb = c >> 4, rr = c & 15;
      int mt = gate*19 + cb, g = rr >> 2, er = rr & 3;
      float bias = bih[j] + (j < 600 ? bhh[j] : 0.f);
      size_t base = ((size_t)t*57 + mt)*256;
      #pragma unroll
      for (int b = 0; b < 10; ++b)
        giP[base + (size_t)(((g<<4)|b)*4 + er)] = (f16)(acc[jp][b] + bias);
    }
  }
}

// ================= K4 v7: 19 WGs x 1 wave, sentinel exchange, de-serialized =================
// r10 protocol (agent-scope atomics, 4-parity sentinel buffer), reordered so
// nothing slow sits in front of the first poll sample:
//   poll(h_t)            [drains only poll loads + fully-overlapped gi stragglers]
//   re-sentinel (t+2)&3  [ack hides under the 30 MFMAs]
//   30 MFMA
//   vmcnt(0)             [re-sentinel acked before publish -> r10 ordering proof]
//   combine + publish h_{t+1}
//   prefetch gi(t+1)     [double-buffered gva/gvb; latency overlaps publish
//                         visibility + backedge + genuine wait for peer data]
// Overwrite-safety: observed h_t ==> peers finished step t-1 ==> their reads of
// h_{t-2} (parity (t+2)&3) are long done.
#define PIN_V(x) asm volatile("" : "+v"(x))

#define STEP_BODY(T, GU, GP)                                                        \
{                                                                                   \
  const int t_ = (T);                                                               \
  /* poll data slots of parity t&3 until all fresh */                               \
  const unsigned long long* hb = hx + (size_t)(t_ & 3)*HPAR;                        \
  unsigned long long v[20];                                                         \
  _Pragma("unroll")                                                                 \
  for (int s = 0; s < 20; ++s) v[s] = need[s] ? SENT : 0ull;                        \
  int rounds = 0; bool all = false;                                                 \
  while (!all){                                                                     \
    _Pragma("unroll")                                                               \
    for (int s = 0; s < 20; ++s){                                                   \
      if (need[s] && v[s] == SENT){                                                 \
        int cg = (s >> 1)*8 + grp*2 + (s & 1);                                      \
        v[s] = __hip_atomic_load(&hb[cg*16 + bl], __ATOMIC_RELAXED, __HIP_MEMORY_SCOPE_AGENT); \
      }                                                                             \
    }                                                                               \
    all = true;                                                                     \
    _Pragma("unroll")                                                               \
    for (int s = 0; s < 20; ++s) all = all && (!need[s] || v[s] != SENT);           \
    if (++rounds > SPIN_ROUNDS) break;                                              \
  }                                                                                 \
  __builtin_amdgcn_sched_barrier(0);                                                \
  /* re-sentinel own slot in parity (t+2)&3 (dead h_{t-2}); acked under MFMA */     \
  if (wv)                                                                           \
    __hip_atomic_store(&hx[(size_t)((t_+2)&3)*HPAR + pslot], SENT,                  \
                       __ATOMIC_RELAXED, __HIP_MEMORY_SCOPE_AGENT);                 \
  f16x8 bf[10];                                                                     \
  _Pragma("unroll")                                                                 \
  for (int kc = 0; kc < 10; ++kc){                                                  \
    union { unsigned long long u[2]; f16x8 w; } cv;                                 \
    cv.u[0] = v[kc*2+0];                                                            \
    cv.u[1] = v[kc*2+1];                                                            \
    bf[kc] = cv.w;                                                                  \
  }                                                                                 \
  f32x4 a0 = {0.f,0.f,0.f,0.f}, a1 = {0.f,0.f,0.f,0.f}, a2 = {0.f,0.f,0.f,0.f};    \
  _Pragma("unroll")                                                                 \
  for (int kc = 0; kc < 10; ++kc){                                                  \
    a0 = __builtin_amdgcn_mfma_f32_16x16x32_f16(areg[0][kc], bf[kc], a0, 0, 0, 0);  \
    a1 = __builtin_amdgcn_mfma_f32_16x16x32_f16(areg[1][kc], bf[kc], a1, 0, 0, 0);  \
    a2 = __builtin_amdgcn_mfma_f32_16x16x32_f16(areg[2][kc], bf[kc], a2, 0, 0, 0);  \
  }                                                                                 \
  asm volatile("s_waitcnt vmcnt(0)" ::: "memory");   /* re-sentinel acked */        \
  if (wv){                                                                          \
    union { f16 h4[4]; unsigned long long u; } pk;                                  \
    _Pragma("unroll")                                                               \
    for (int rg = 0; rg < 4; ++rg){                                                 \
      float r  = sigm_(a0[rg] + (float)GU[0][rg]);                                  \
      float z  = sigm_(a1[rg] + (float)GU[1][rg]);                                  \
      float n  = tanh_((float)GU[2][rg] + r*(a2[rg] + bhhN[rg]));                   \
      float hn = (1.f - z)*n + z*hreg[rg];                                          \
      hreg[rg] = hn;                                                                \
      pk.h4[rg] = (f16)hn;                                                          \
    }                                                                               \
    __hip_atomic_store(&hx[(size_t)((t_+1)&3)*HPAR + pslot], pk.u,                  \
                       __ATOMIC_RELAXED, __HIP_MEMORY_SCOPE_AGENT);                 \
  }                                                                                 \
  {  /* prefetch gi(t+1) AFTER publish — consumed next step */                      \
    int tn = imin_(t_ + 1, 2047);                                                   \
    const f16* gpp = giP + (size_t)tn*14592;                                        \
    _Pragma("unroll")                                                               \
    for (int gate = 0; gate < 3; ++gate)                                            \
      GP[gate] = *(const f16x4*)&gpp[(size_t)((gate*19+cb)*64 + l)*4];              \
  }                                                                                 \
}

__global__ __launch_bounds__(64, 1) void k4_mesh(
    const f16* __restrict__ WhhP, const f16* __restrict__ giP,
    const float* __restrict__ mI, const float* __restrict__ bhh,
    unsigned long long* hx, float* __restrict__ hout)
{
  const int cb = blockIdx.x, l = threadIdx.x;
  const int bl = l & 15, grp = l >> 4;
  const int c0 = cb*16 + grp*4;          // this lane's output rows (as producer)
  const bool wv = (c0 < 300) && (bl < 10);
  const int pslot = (cb*4 + grp)*16 + bl; // publish slot index

  // resident A fragments: 3 gates x 10 kc (120 VGPRs), pinned
  f16x8 areg[3][10];
  #pragma unroll
  for (int gate = 0; gate < 3; ++gate){
    const int mt = gate*19 + cb;
    #pragma unroll
    for (int kc = 0; kc < 10; ++kc)
      areg[gate][kc] = *(const f16x8*)&WhhP[((size_t)(mt*10+kc)*64 + l)*8];
  }
  #pragma unroll
  for (int gate = 0; gate < 3; ++gate)
    #pragma unroll
    for (int kc = 0; kc < 10; ++kc)
      PIN_V(areg[gate][kc]);

  // consumer slot validity: slot_s for s = kc*2+j is ((kc*8+grp*2+j)*16 + bl)
  bool need[20];
  #pragma unroll
  for (int s = 0; s < 20; ++s){
    int cg = (s >> 1)*8 + grp*2 + (s & 1);
    need[s] = (cg < 75) && (bl < 10);
  }

  // h0 master (f32) + n-gate bias
  float hreg[4], bhhN[4];
  #pragma unroll
  for (int rg = 0; rg < 4; ++rg){
    int c = imin_(c0 + rg, 299);
    hreg[rg] = wv ? mI[bl*300 + c] : 0.f;
    bhhN[rg] = (c0 + rg < 300) ? bhh[600 + c] : 0.f;
  }
  // publish h0 into parity 0 (rest of buffer is sentinel from memset)
  if (wv){
    union { f16 h4[4]; unsigned long long u; } pk;
    #pragma unroll
    for (int rg = 0; rg < 4; ++rg) pk.h4[rg] = (f16)hreg[rg];
    __hip_atomic_store(&hx[pslot], pk.u, __ATOMIC_RELAXED, __HIP_MEMORY_SCOPE_AGENT);
  }

  // gi(0) preload (double-buffered thereafter)
  f16x4 gva[3], gvb[3];
  #pragma unroll
  for (int gate = 0; gate < 3; ++gate)
    gva[gate] = *(const f16x4*)&giP[(size_t)((gate*19+cb)*64 + l)*4];

  for (int t = 0; t < 2048; t += 2){
    STEP_BODY(t,     gva, gvb)
    STEP_BODY((t+1), gvb, gva)
  }

  // final h (exact f32 master)
  if (wv){
    #pragma unroll
    for (int rg = 0; rg < 4; ++rg)
      hout[bl*300 + c0 + rg] = hreg[rg];
  }
}

// ================= launch =================
extern "C" void kernel_launch(void* const* d_in, const int* in_sizes, int n_in,
                              void* d_out, int out_size, void* d_ws, size_t ws_size,
                              hipStream_t stream)
{
  const float* cs   = (const float*)d_in[0];
  const float* m    = (const float*)d_in[1];
  const float* q    = (const float*)d_in[2];
  const float* mask = (const float*)d_in[3];
  const float* Wb   = (const float*)d_in[4];
  const float* W1   = (const float*)d_in[5];
  const float* b1   = (const float*)d_in[6];
  const float* W2   = (const float*)d_in[7];
  const float* b2   = (const float*)d_in[8];
  const float* Wih  = (const float*)d_in[9];
  const float* Whh  = (const float*)d_in[10];
  const float* bih  = (const float*)d_in[11];
  const float* bhh  = (const float*)d_in[12];
  float* out = (float*)d_out;
  char* ws = (char*)d_ws;
  float* Gs   = (float*)(ws + WS_GS);
  float* QM   = (float*)(ws + WS_QM);
  float* CB   = (float*)(ws + WS_CB);
  f16*   W1T  = (f16*)(ws + WS_W1T);
  f16*   WhhP = (f16*)(ws + WS_WHHP);
  f16*   giP  = (f16*)(ws + WS_GIP);
  unsigned long long* hx = (unsigned long long*)(ws + WS_HX);

  k0_prep<<<dim3(1), dim3(512), 0, stream>>>(q, m, W1, b1, QM, CB, W1T);
  k_pack<<<dim3(570), dim3(64), 0, stream>>>(Whh, WhhP);
  k1_attn<<<dim3(256), dim3(512), 0, stream>>>(cs, m, q, mask, Wb, W2, b2, QM, CB, W1T, out);
  k2_softmax<<<dim3(10), dim3(256), 0, stream>>>(out, Gs);
  k3_gi<<<dim3(2048), dim3(256), 0, stream>>>(cs, Gs, Wih, bih, bhh, giP);
  // W1T region dead after k1 -> sentinel-fill the 4-parity exchange buffer
  hipMemsetAsync(ws + WS_HX, 0xFF, 4*HPAR*8, stream);
  k4_mesh<<<dim3(19), dim3(64), 0, stream>>>(WhhP, giP, m, bhh, hx, out + 20480);
}

// Round 14
// 5143.719 us; speedup vs baseline: 1.1926x; 1.1926x over previous
//
#include <hip/hip_runtime.h>
#include <hip/hip_fp16.h>
#include <cstdint>
#include <cstddef>

typedef _Float16 f16;
typedef _Float16 f16x8 __attribute__((ext_vector_type(8)));
typedef _Float16 f16x4 __attribute__((ext_vector_type(4)));
typedef float    f32x4 __attribute__((ext_vector_type(4)));

// ---------------- ws layout (bytes) ----------------
// Gs   f32 [2048][10]                :      0 ..  81920
// QM   f32 [10][16]                  :  81920 ..  82560
// CB   f32 [10][16]                  :  82560 ..  83200
// W1T  f16 [16][5][4][80]            :  83200 .. 134400   (dead after k1)
//   hx  u64 [4][1216]   (overlay)    :  83200 .. 122112   (sentinel exchange)
// WhhP f16 [57*10][64][8]            : 134400 .. 718080
// giP  f16 [2048][57][64][4]         : 718080 .. 60486912
#define WS_GS    0u
#define WS_QM    81920u
#define WS_CB    82560u
#define WS_W1T   83200u
#define WS_HX    83200u
#define WS_WHHP  134400u
#define WS_GIP   718080u

#define HPAR 1216        // u64 per parity: 76 cg * 16 bl
#define SENT 0xFFFFFFFFFFFFFFFFull
#define SPIN_ROUNDS 200000

__device__ __forceinline__ float sigm_(float x){ return 1.0f/(1.0f + __expf(-x)); }
__device__ __forceinline__ float tanh_(float x){
  float ax = fabsf(x);
  float e  = __expf(-2.0f*ax);
  float r  = (1.0f - e)/(1.0f + e);
  return x < 0.0f ? -r : r;
}
__device__ __forceinline__ int imin_(int a,int b){ return a<b?a:b; }

// ================= K0: prep (QM, CB, W1T) =================
__global__ __launch_bounds__(512) void k0_prep(
    const float* __restrict__ q, const float* __restrict__ m,
    const float* __restrict__ W1, const float* __restrict__ b1,
    float* __restrict__ QM, float* __restrict__ CBo, f16* __restrict__ W1T)
{
  int tid = threadIdx.x;
  if (tid < 160){
    int k = tid >> 4, h = tid & 15;
    float acc = 0.f;
    for (int d = 0; d < 300; ++d)
      acc += q[k*300+d]*W1[(2100+d)*16+h] + m[k*300+d]*W1[(2400+d)*16+h];
    QM[tid] = acc;
  } else if (tid < 320){
    int b = (tid-160) >> 4, h = tid & 15;
    float acc = b1[h];
    for (int d = 0; d < 300; ++d)
      acc += m[b*300+d]*W1[(300+d)*16+h] + q[b*300+d]*W1[(600+d)*16+h];
    CBo[tid-160] = acc;
  }
  const int blkoff[5] = {0, 900, 1200, 1500, 1800};
  for (int i = tid; i < 25600; i += 512){
    int ii = i % 80; int r = i / 80;
    int dg = r % 4; r /= 4;
    int blk = r % 5; int h = r / 5;
    int d = dg*80 + ii;
    float v = 0.f;
    if (d < 300) v = W1[(blkoff[blk]+d)*16 + h];
    W1T[i] = (f16)v;
  }
}

// ================= Kpack: Whh -> MFMA A-fragment layout (f16) =================
__global__ __launch_bounds__(64) void k_pack(const float* __restrict__ Whh, f16* __restrict__ WhhP)
{
  int bid = blockIdx.x, l = threadIdx.x;
  int mt = bid / 10, kc = bid % 10;
  int gate = mt / 19, cb = mt % 19;
  int rr = l & 15, grp = l >> 4;
  int c = cb*16 + rr;
  int j = gate*300 + imin_(c, 299);
  f16x8 v;
  #pragma unroll
  for (int e = 0; e < 8; ++e){
    int d = kc*32 + grp*8 + e;
    float x = Whh[(size_t)imin_(d,299)*900 + j];
    v[e] = (f16)((d < 300 && c < 300) ? x : 0.f);
  }
  *(f16x8*)&WhhP[((size_t)bid*64 + l)*8] = v;
}

// ================= K1: attention gate -> G[b][t] (d_out[0:20480]) =================
__global__ __launch_bounds__(512) void k1_attn(
    const float* __restrict__ cs, const float* __restrict__ mI, const float* __restrict__ qI,
    const float* __restrict__ mask, const float* __restrict__ Wb,
    const float* __restrict__ W2, const float* __restrict__ b2,
    const float* __restrict__ QMg, const float* __restrict__ CBg, const f16* __restrict__ W1Tg,
    float* __restrict__ Gout)
{
  __shared__ __align__(16) float q_s[3000];
  __shared__ __align__(16) float m_s[3000];
  __shared__ float Wb_s[3000];
  __shared__ float QM_s[160], CB_s[160], W2_s[16];
  __shared__ __align__(16) f16 W1T_s[25600];
  __shared__ float cwb_s[8][10][10];
  int tid = threadIdx.x;
  for (int i = tid; i < 3000; i += 512){ q_s[i] = qI[i]; m_s[i] = mI[i]; Wb_s[i] = Wb[i]; }
  for (int i = tid; i < 160; i += 512){ QM_s[i] = QMg[i]; CB_s[i] = CBg[i]; }
  if (tid < 16) W2_s[tid] = W2[tid];
  for (int i = tid; i < 25600; i += 512) W1T_s[i] = W1Tg[i];
  __syncthreads();

  int w = tid >> 6, l = tid & 63, dg = l >> 4, lo = l & 15;
  int t = blockIdx.x*8 + w;
  float a[10], cwb[10];
  #pragma unroll
  for (int b = 0; b < 10; ++b){ a[b] = 0.f; cwb[b] = 0.f; }

  for (int i = 0; i < 10; ++i){
    int d0 = dg*80 + i*8;
    const int wbase = lo*1600 + dg*80 + i*8;
    f16x8 wf0 = *(const f16x8*)&W1T_s[wbase + 0*320];
    f16x8 wf1 = *(const f16x8*)&W1T_s[wbase + 1*320];
    f16x8 wf2 = *(const f16x8*)&W1T_s[wbase + 2*320];
    f16x8 wf3 = *(const f16x8*)&W1T_s[wbase + 3*320];
    f16x8 wf4 = *(const f16x8*)&W1T_s[wbase + 4*320];
    int dc0 = imin_(d0, 296), dc1 = imin_(d0 + 4, 296);
    #pragma unroll
    for (int b = 0; b < 10; ++b){
      const float* csb = cs + ((size_t)t*10 + b)*300;
      float4 c0 = *(const float4*)(csb + dc0);
      float4 c1 = *(const float4*)(csb + dc1);
      float4 q0 = *(const float4*)(q_s + b*300 + dc0);
      float4 q1 = *(const float4*)(q_s + b*300 + dc1);
      float4 m0 = *(const float4*)(m_s + b*300 + dc0);
      float4 m1 = *(const float4*)(m_s + b*300 + dc1);
      float cv[8] = {c0.x,c0.y,c0.z,c0.w,c1.x,c1.y,c1.z,c1.w};
      float qv[8] = {q0.x,q0.y,q0.z,q0.w,q1.x,q1.y,q1.z,q1.w};
      float mv[8] = {m0.x,m0.y,m0.z,m0.w,m1.x,m1.y,m1.z,m1.w};
      #pragma unroll
      for (int e = 0; e < 8; ++e){
        int d = d0 + e;
        float cvv = cv[e];
        a[b] += cvv*(float)wf0[e] + (cvv*qv[e])*(float)wf1[e] + (cvv*mv[e])*(float)wf2[e]
              + fabsf(cvv - qv[e])*(float)wf3[e] + fabsf(cvv - mv[e])*(float)wf4[e];
        float wv = Wb_s[imin_(d, 299)*10 + imin_(lo, 9)];
        wv = (lo < 10 && d < 300) ? wv : 0.f;
        cwb[b] += cvv*wv;
      }
    }
  }
  #pragma unroll
  for (int b = 0; b < 10; ++b){
    float v = cwb[b];
    v += __shfl_xor(v, 16, 64);
    v += __shfl_xor(v, 32, 64);
    cwb[b] = v;
  }
  if (dg == 0 && lo < 10){
    #pragma unroll
    for (int b = 0; b < 10; ++b) cwb_s[w][b][lo] = cwb[b];
  }
  __asm__ volatile("s_waitcnt lgkmcnt(0)" ::: "memory");
  __builtin_amdgcn_sched_barrier(0);
  float b2v = b2[0];
  #pragma unroll
  for (int b = 0; b < 10; ++b){
    float cross = 0.f;
    #pragma unroll
    for (int k = 0; k < 10; ++k) cross += cwb_s[w][b][k]*QM_s[k*16 + lo];
    float v = a[b];
    v += __shfl_xor(v, 16, 64);
    v += __shfl_xor(v, 32, 64);
    v += CB_s[b*16 + lo] + cross;
    float tv = tanh_(v)*W2_s[lo];
    tv += __shfl_xor(tv, 1, 64);
    tv += __shfl_xor(tv, 2, 64);
    tv += __shfl_xor(tv, 4, 64);
    tv += __shfl_xor(tv, 8, 64);
    a[b] = sigm_(tv + b2v);
  }
  if (l == 0){
    #pragma unroll
    for (int b = 0; b < 10; ++b) Gout[b*2048 + t] = a[b]*mask[t*10 + b];
  }
}

// ================= K2: softmax over T per b: Gs[t][b] =================
__global__ __launch_bounds__(256) void k2_softmax(const float* __restrict__ G, float* __restrict__ Gs)
{
  int b = blockIdx.x, tid = threadIdx.x;
  __shared__ float red[4];
  float v[8];
  #pragma unroll
  for (int k = 0; k < 8; ++k) v[k] = G[b*2048 + tid + k*256];
  float mx = v[0];
  #pragma unroll
  for (int k = 1; k < 8; ++k) mx = fmaxf(mx, v[k]);
  #pragma unroll
  for (int off = 1; off < 64; off <<= 1) mx = fmaxf(mx, __shfl_xor(mx, off, 64));
  if ((tid & 63) == 0) red[tid >> 6] = mx;
  __syncthreads();
  mx = fmaxf(fmaxf(red[0], red[1]), fmaxf(red[2], red[3]));
  __syncthreads();
  float e[8], s = 0.f;
  #pragma unroll
  for (int k = 0; k < 8; ++k){ e[k] = __expf(v[k]-mx); s += e[k]; }
  #pragma unroll
  for (int off = 1; off < 64; off <<= 1) s += __shfl_xor(s, off, 64);
  if ((tid & 63) == 0) red[tid >> 6] = s;
  __syncthreads();
  s = red[0]+red[1]+red[2]+red[3];
  float inv = 1.0f / s;
  #pragma unroll
  for (int k = 0; k < 8; ++k) Gs[(tid + k*256)*10 + b] = e[k]*inv;
}

// ================= K3: gi[t] = seq[t] @ Wih + bih (+bhh folded for r,z) =================
__global__ __launch_bounds__(256) void k3_gi(
    const float* __restrict__ cs, const float* __restrict__ Gs,
    const float* __restrict__ Wih, const float* __restrict__ bih, const float* __restrict__ bhh,
    f16* __restrict__ giP)
{
  int t = blockIdx.x, tid = threadIdx.x;
  __shared__ __align__(16) float sfT[300*16];
  for (int i = tid; i < 3000; i += 256){
    int d = i / 10, bcol = i % 10;
    int jj = d % 10;
    sfT[d*16 + bcol] = Gs[t*10 + jj] * cs[((size_t)t*10 + jj)*300 + bcol*30 + d/10];
  }
  __syncthreads();
  float acc[4][10];
  #pragma unroll
  for (int jp = 0; jp < 4; ++jp)
    #pragma unroll
    for (int b = 0; b < 10; ++b) acc[jp][b] = 0.f;
  for (int d = 0; d < 300; ++d){
    float4 s0 = *(const float4*)&sfT[d*16 + 0];
    float4 s1 = *(const float4*)&sfT[d*16 + 4];
    float4 s2 = *(const float4*)&sfT[d*16 + 8];
    float sb[10] = {s0.x,s0.y,s0.z,s0.w, s1.x,s1.y,s1.z,s1.w, s2.x,s2.y};
    #pragma unroll
    for (int jp = 0; jp < 4; ++jp){
      int j = jp*256 + tid;
      float wv = Wih[(size_t)d*900 + imin_(j, 899)];
      wv = (j < 900) ? wv : 0.f;
      #pragma unroll
      for (int b = 0; b < 10; ++b) acc[jp][b] += wv * sb[b];
    }
  }
  #pragma unroll
  for (int jp = 0; jp < 4; ++jp){
    int j = jp*256 + tid;
    if (j < 900){
      int gate = j / 300, c = j - gate*300;
      int cb = c >> 4, rr = c & 15;
      int mt = gate*19 + cb, g = rr >> 2, er = rr & 3;
      float bias = bih[j] + (j < 600 ? bhh[j] : 0.f);
      size_t base = ((size_t)t*57 + mt)*256;
      #pragma unroll
      for (int b = 0; b < 10; ++b)
        giP[base + (size_t)(((g<<4)|b)*4 + er)] = (f16)(acc[jp][b] + bias);
    }
  }
}

// ================= K4 v5: 19 WGs x 1 wave, sentinel exchange (no flags) =================
// h_s lives in parity s&3; slot for 4-col group cg = c/4 and batch bl is
// hx[par*HPAR + cg*16 + bl] (u64 = 4 f16). Slots pre-filled with SENT
// (f16 NaN pattern unreachable from (f16)(finite)). Consumers poll data
// slots directly until != SENT -> publish->observe is ~1.5 MALL RTTs.
// Re-sentinel: at step t each producer refills its slots in parity (t+2)&3
// (holds dead h_{t-2} by the skew invariant); one s_waitcnt vmcnt(0) before
// publish makes fills causally visible before the next h (wait is on stores
// issued a full step earlier -> free).
#define PIN_V(x) asm volatile("" : "+v"(x))

__global__ __launch_bounds__(64, 1) void k4_mesh(
    const f16* __restrict__ WhhP, const f16* __restrict__ giP,
    const float* __restrict__ mI, const float* __restrict__ bhh,
    unsigned long long* hx, float* __restrict__ hout)
{
  const int cb = blockIdx.x, l = threadIdx.x;
  const int bl = l & 15, grp = l >> 4;
  const int c0 = cb*16 + grp*4;          // this lane's output rows (as producer)
  const bool wv = (c0 < 300) && (bl < 10);
  const int pslot = (cb*4 + grp)*16 + bl; // publish slot index

  // resident A fragments: 3 gates x 10 kc (120 VGPRs), pinned
  f16x8 areg[3][10];
  #pragma unroll
  for (int gate = 0; gate < 3; ++gate){
    const int mt = gate*19 + cb;
    #pragma unroll
    for (int kc = 0; kc < 10; ++kc)
      areg[gate][kc] = *(const f16x8*)&WhhP[((size_t)(mt*10+kc)*64 + l)*8];
  }
  #pragma unroll
  for (int gate = 0; gate < 3; ++gate)
    #pragma unroll
    for (int kc = 0; kc < 10; ++kc)
      PIN_V(areg[gate][kc]);

  // consumer slot validity: slot_s for s = kc*2+j is ((kc*8+grp*2+j)*16 + bl)
  bool need[20];
  #pragma unroll
  for (int s = 0; s < 20; ++s){
    int cg = (s >> 1)*8 + grp*2 + (s & 1);
    need[s] = (cg < 75) && (bl < 10);
  }

  // h0 master (f32) + n-gate bias
  float hreg[4], bhhN[4];
  #pragma unroll
  for (int rg = 0; rg < 4; ++rg){
    int c = imin_(c0 + rg, 299);
    hreg[rg] = wv ? mI[bl*300 + c] : 0.f;
    bhhN[rg] = (c0 + rg < 300) ? bhh[600 + c] : 0.f;
  }
  // publish h0 into parity 0 (rest of buffer is sentinel from memset)
  if (wv){
    union { f16 h4[4]; unsigned long long u; } pk;
    #pragma unroll
    for (int rg = 0; rg < 4; ++rg) pk.h4[rg] = (f16)hreg[rg];
    __hip_atomic_store(&hx[pslot], pk.u, __ATOMIC_RELAXED, __HIP_MEMORY_SCOPE_AGENT);
  }

  for (int t = 0; t < 2048; ++t){
    // re-sentinel own slot in parity (t+2)&3 (holds dead h_{t-2})
    if (wv)
      __hip_atomic_store(&hx[(size_t)((t+2)&3)*HPAR + pslot], SENT,
                         __ATOMIC_RELAXED, __HIP_MEMORY_SCOPE_AGENT);

    // gi for this step — independent of h, issue before the exchange
    f16x4 gv[3];
    const f16* gp = giP + (size_t)t*14592;
    #pragma unroll
    for (int gate = 0; gate < 3; ++gate)
      gv[gate] = *(const f16x4*)&gp[(size_t)((gate*19+cb)*64 + l)*4];

    // poll data slots of parity t&3 until all fresh
    const unsigned long long* hb = hx + (size_t)(t & 3)*HPAR;
    unsigned long long v[20];
    #pragma unroll
    for (int s = 0; s < 20; ++s) v[s] = need[s] ? SENT : 0ull;
    int rounds = 0;
    bool all = false;
    while (!all){
      all = true;
      #pragma unroll
      for (int s = 0; s < 20; ++s){
        if (need[s] && v[s] == SENT){
          int cg = (s >> 1)*8 + grp*2 + (s & 1);
          v[s] = __hip_atomic_load(&hb[cg*16 + bl], __ATOMIC_RELAXED, __HIP_MEMORY_SCOPE_AGENT);
        }
      }
      #pragma unroll
      for (int s = 0; s < 20; ++s) all = all && (!need[s] || v[s] != SENT);
      if (++rounds > SPIN_ROUNDS) break;   // fail-fast: wrong answer, no hang
    }
    __builtin_amdgcn_sched_barrier(0);

    // assemble B fragments
    f16x8 bf[10];
    #pragma unroll
    for (int kc = 0; kc < 10; ++kc){
      union { unsigned long long u[2]; f16x8 v; } cv;
      cv.u[0] = v[kc*2+0];
      cv.u[1] = v[kc*2+1];
      bf[kc] = cv.v;
    }

    // 30 MFMA, 3 independent chains
    f32x4 a0 = {0.f,0.f,0.f,0.f}, a1 = {0.f,0.f,0.f,0.f}, a2 = {0.f,0.f,0.f,0.f};
    #pragma unroll
    for (int kc = 0; kc < 10; ++kc){
      a0 = __builtin_amdgcn_mfma_f32_16x16x32_f16(areg[0][kc], bf[kc], a0, 0, 0, 0);
      a1 = __builtin_amdgcn_mfma_f32_16x16x32_f16(areg[1][kc], bf[kc], a1, 0, 0, 0);
      a2 = __builtin_amdgcn_mfma_f32_16x16x32_f16(areg[2][kc], bf[kc], a2, 0, 0, 0);
    }

    // in-lane combine + publish h_{t+1} into parity (t+1)&3
    asm volatile("s_waitcnt vmcnt(0)" ::: "memory");   // fills (issued ~1 step ago) acked
    if (wv){
      union { f16 h4[4]; unsigned long long u; } pk;
      #pragma unroll
      for (int rg = 0; rg < 4; ++rg){
        float r  = sigm_(a0[rg] + (float)gv[0][rg]);
        float z  = sigm_(a1[rg] + (float)gv[1][rg]);
        float n  = tanh_((float)gv[2][rg] + r*(a2[rg] + bhhN[rg]));
        float hn = (1.f - z)*n + z*hreg[rg];
        hreg[rg] = hn;
        pk.h4[rg] = (f16)hn;
      }
      __hip_atomic_store(&hx[(size_t)((t+1)&3)*HPAR + pslot], pk.u,
                         __ATOMIC_RELAXED, __HIP_MEMORY_SCOPE_AGENT);
    }
  }

  // final h (exact f32 master)
  if (wv){
    #pragma unroll
    for (int rg = 0; rg < 4; ++rg)
      hout[bl*300 + c0 + rg] = hreg[rg];
  }
}

// ================= launch =================
extern "C" void kernel_launch(void* const* d_in, const int* in_sizes, int n_in,
                              void* d_out, int out_size, void* d_ws, size_t ws_size,
                              hipStream_t stream)
{
  const float* cs   = (const float*)d_in[0];
  const float* m    = (const float*)d_in[1];
  const float* q    = (const float*)d_in[2];
  const float* mask = (const float*)d_in[3];
  const float* Wb   = (const float*)d_in[4];
  const float* W1   = (const float*)d_in[5];
  const float* b1   = (const float*)d_in[6];
  const float* W2   = (const float*)d_in[7];
  const float* b2   = (const float*)d_in[8];
  const float* Wih  = (const float*)d_in[9];
  const float* Whh  = (const float*)d_in[10];
  const float* bih  = (const float*)d_in[11];
  const float* bhh  = (const float*)d_in[12];
  float* out = (float*)d_out;
  char* ws = (char*)d_ws;
  float* Gs   = (float*)(ws + WS_GS);
  float* QM   = (float*)(ws + WS_QM);
  float* CB   = (float*)(ws + WS_CB);
  f16*   W1T  = (f16*)(ws + WS_W1T);
  f16*   WhhP = (f16*)(ws + WS_WHHP);
  f16*   giP  = (f16*)(ws + WS_GIP);
  unsigned long long* hx = (unsigned long long*)(ws + WS_HX);

  k0_prep<<<dim3(1), dim3(512), 0, stream>>>(q, m, W1, b1, QM, CB, W1T);
  k_pack<<<dim3(570), dim3(64), 0, stream>>>(Whh, WhhP);
  k1_attn<<<dim3(256), dim3(512), 0, stream>>>(cs, m, q, mask, Wb, W2, b2, QM, CB, W1T, out);
  k2_softmax<<<dim3(10), dim3(256), 0, stream>>>(out, Gs);
  k3_gi<<<dim3(2048), dim3(256), 0, stream>>>(cs, Gs, Wih, bih, bhh, giP);
  // W1T region dead after k1 -> sentinel-fill the 4-parity exchange buffer
  hipMemsetAsync(ws + WS_HX, 0xFF, 4*HPAR*8, stream);
  k4_mesh<<<dim3(19), dim3(64), 0, stream>>>(WhhP, giP, m, bhh, hx, out + 20480);
}